// Round 5
// baseline (380.179 us; speedup 1.0000x reference)
//
#include <hip/hip_runtime.h>
#include <hip/hip_bf16.h>
#include <float.h>
#include <stdint.h>

// Problem constants (fixed by setup_inputs): B=4, N=M=4096, D=3.
#define BATCH 4
#define NPTS  4096
#define TOT   (BATCH * NPTS)   // 16384
#define NSTRIPE 16             // stripes per own point: stripe s = {j : j % 16 == s}
#define SPAN    (NPTS / NSTRIPE) // 256 candidates per stripe

// ---------------------------------------------------------------------------
// Kernel 1: pack points into float4 {x, y, z, |p|^2}.
// rr computed as x*x + y*y + z*z left-to-right, matching jnp.sum(x*x, -1).
// ---------------------------------------------------------------------------
__global__ __launch_bounds__(256) void pack_kernel(
    const float* __restrict__ gts, const float* __restrict__ preds,
    float4* __restrict__ pkG, float4* __restrict__ pkP)
{
    int i = blockIdx.x * blockDim.x + threadIdx.x;   // 0 .. 2*TOT-1
    if (i >= 2 * TOT) return;
    const float* src = (i < TOT) ? gts : preds;
    float4* dst      = (i < TOT) ? pkG : pkP;
    int k            = (i < TOT) ? i : i - TOT;
    float x = src[3 * k + 0];
    float y = src[3 * k + 1];
    float z = src[3 * k + 2];
    float rr = __fadd_rn(__fadd_rn(__fmul_rn(x, x), __fmul_rn(y, y)), __fmul_rn(z, z));
    dst[k] = make_float4(x, y, z, rr);
}

// ---------------------------------------------------------------------------
// Round 0 (full scan, both directions in one launch) + stripe-partial store.
// 8 rows per wave. Lane l scans j ≡ l (mod 64); strict '<' keeps first
// (smallest-j) min per lane. Butterfly xor{16,32} first: lane l then holds
// the min over lanes {l, l^16, l^32, l^48} = stripe (l & 15); lanes 0-15
// store the 16 stripe partials as {float_bits(d), idx}. Continue xor{1..8}
// for the global (d, idx); lexicographic compare = numpy argmin tie-break.
// ---------------------------------------------------------------------------
__global__ __launch_bounds__(256) void round0_kernel(
    const float4* __restrict__ pkG, const float4* __restrict__ pkP,
    float* __restrict__ dS, int* __restrict__ iS,
    float* __restrict__ dF, int* __restrict__ iF,
    int2* __restrict__ stripes)   // [2][TOT][NSTRIPE]
{
    int wid  = blockIdx.x * 4 + (threadIdx.x >> 6);   // 0..4095
    int lane = threadIdx.x & 63;
    bool isRow = wid < 2048;
    int w = isRow ? wid : wid - 2048;
    int ownBase = w * 8;                 // 8 | 4096 -> no batch straddle
    int b = ownBase >> 12;
    int obase = b << 12;

    const float4* own = isRow ? pkG : pkP;
    const float4* oth = isRow ? pkP : pkG;
    float* dOut = isRow ? dS : dF;
    int*   iOut = isRow ? iS : iF;
    int dirOfs  = isRow ? 0 : TOT;

    float ox[8], oy[8], oz[8], orr[8];
    #pragma unroll
    for (int r = 0; r < 8; ++r) {
        float4 p = own[ownBase + r];
        ox[r] = p.x; oy[r] = p.y; oz[r] = p.z; orr[r] = p.w;
    }
    float best[8]; int bidx[8];
    #pragma unroll
    for (int r = 0; r < 8; ++r) { best[r] = FLT_MAX; bidx[r] = 0; }

    const float4* qp = oth + obase + lane;
    #pragma unroll 2
    for (int t = 0; t < 64; ++t) {
        float4 q = qp[t * 64];
        int j = lane + (t << 6);
        #pragma unroll
        for (int r = 0; r < 8; ++r) {
            // zz left-to-right, no contraction (matches the verified round-3 kernel)
            float zz = __fadd_rn(__fadd_rn(__fmul_rn(ox[r], q.x),
                                           __fmul_rn(oy[r], q.y)),
                                 __fmul_rn(oz[r], q.z));
            // fma(-2,zz,s) == s - 2*zz (single rounding, 2*zz exact)
            float d = __fmaf_rn(-2.0f, zz, __fadd_rn(orr[r], q.w));
            if (d < best[r]) { best[r] = d; bidx[r] = j; }
        }
    }

    #pragma unroll
    for (int r = 0; r < 8; ++r) {
        float v = best[r]; int ix = bidx[r];
        #pragma unroll
        for (int off = 16; off <= 32; off <<= 1) {
            float v2 = __shfl_xor(v, off);
            int   i2 = __shfl_xor(ix, off);
            if (v2 < v || (v2 == v && i2 < ix)) { v = v2; ix = i2; }
        }
        if (lane < NSTRIPE)
            stripes[((size_t)(dirOfs + ownBase + r) << 4) + lane] =
                make_int2(__float_as_int(v), ix);
        #pragma unroll
        for (int off = 1; off <= 8; off <<= 1) {
            float v2 = __shfl_xor(v, off);
            int   i2 = __shfl_xor(ix, off);
            if (v2 < v || (v2 == v && i2 < ix)) { v = v2; ix = i2; }
        }
        if (lane == 0) { iOut[ownBase + r] = ix; dOut[ownBase + r] = v; }
    }
}

// ---------------------------------------------------------------------------
// Rounds 1-3 via stripe invalidation. One wave per (direction, own point).
// A stored stripe min is valid under the cumulative exclusion set unless its
// winner is excluded; invalid stripes (rarely >2) are rescanned with full
// exclusion tests. Exclusion of candidate j for own i (row dir; col mirrors):
//   j == i_s2f_t[i]  OR  i_f2s_t[j] == i   for any t < R.
// ---------------------------------------------------------------------------
template<int R>
__global__ __launch_bounds__(256) void roundR_kernel(
    const float4* __restrict__ pkG, const float4* __restrict__ pkP,
    const int2* __restrict__ stripes,
    const int* __restrict__ is0, const int* __restrict__ is1, const int* __restrict__ is2,
    const int* __restrict__ if0, const int* __restrict__ if1, const int* __restrict__ if2,
    int* __restrict__ iS, int* __restrict__ iF,
    int do_rows)
{
    int wid  = blockIdx.x * 4 + (threadIdx.x >> 6);
    int lane = threadIdx.x & 63;
    int half = do_rows ? TOT : 0;
    bool isRow = wid < half;
    int i = isRow ? wid : wid - half;        // global own index, 0..TOT-1

    const float4* ownp = isRow ? pkG : pkP;
    const float4* oth  = isRow ? pkP : pkG;
    const int* exOwn0 = isRow ? is0 : if0;
    const int* exOwn1 = isRow ? is1 : if1;
    const int* exOwn2 = isRow ? is2 : if2;
    const int* exOth0 = isRow ? if0 : is0;
    const int* exOth1 = isRow ? if1 : is1;
    const int* exOth2 = isRow ? if2 : is2;
    int* iOut  = isRow ? iS : iF;
    int dirOfs = isRow ? 0 : TOT;

    int b = i >> 12;
    int obase = b << 12;
    int ownIn = i & (NPTS - 1);

    int e0 = exOwn0[i];
    int e1 = (R > 1) ? exOwn1[i] : -1;
    int e2 = (R > 2) ? exOwn2[i] : -1;

    bool excl = false;
    int2 key = make_int2(0, 0);
    if (lane < NSTRIPE) {
        key = stripes[((size_t)(dirOfs + i) << 4) + lane];
        int jw = key.y;
        excl = (jw == e0) || (exOth0[obase + jw] == ownIn);
        if (R > 1) excl = excl || (jw == e1) || (exOth1[obase + jw] == ownIn);
        if (R > 2) excl = excl || (jw == e2) || (exOth2[obase + jw] == ownIn);
    }
    unsigned long long mask = __ballot(excl);   // only lanes < 16 can be set

    float kd = (lane < NSTRIPE && !excl) ? __int_as_float(key.x) : FLT_MAX;
    int   kj = (lane < NSTRIPE && !excl) ? key.y : 0x7FFFFFFF;

    if (mask) {
        float4 p = ownp[i];
        while (mask) {
            int s = __ffsll(mask) - 1;          // wave-uniform
            mask &= mask - 1;
            #pragma unroll
            for (int it = 0; it < 4; ++it) {
                int j = s + (((it << 6) + lane) << 4);   // s + 16*(it*64+lane)
                float4 q = oth[obase + j];
                float zz = __fadd_rn(__fadd_rn(__fmul_rn(p.x, q.x),
                                               __fmul_rn(p.y, q.y)),
                                     __fmul_rn(p.z, q.z));
                float d = __fmaf_rn(-2.0f, zz, __fadd_rn(p.w, q.w));
                bool ex = (j == e0) || (exOth0[obase + j] == ownIn);
                if (R > 1) ex = ex || (j == e1) || (exOth1[obase + j] == ownIn);
                if (R > 2) ex = ex || (j == e2) || (exOth2[obase + j] == ownIn);
                if (!ex && (d < kd || (d == kd && j < kj))) { kd = d; kj = j; }
            }
        }
    }

    #pragma unroll
    for (int off = 1; off < 64; off <<= 1) {
        float v2 = __shfl_xor(kd, off);
        int   i2 = __shfl_xor(kj, off);
        if (v2 < kd || (v2 == kd && i2 < kj)) { kd = v2; kj = i2; }
    }
    if (lane == 0) iOut[i] = kj;
}

// ---------------------------------------------------------------------------
// Fallback full-rescan kernel (the verified round-3 version) — used only if
// ws_size is too small for the stripe buffer.
// ---------------------------------------------------------------------------
template<int R>
__global__ __launch_bounds__(256) void round_full_kernel(
    const float4* __restrict__ pkG, const float4* __restrict__ pkP,
    const int* __restrict__ is0, const int* __restrict__ is1, const int* __restrict__ is2,
    const int* __restrict__ if0, const int* __restrict__ if1, const int* __restrict__ if2,
    float* __restrict__ dS, int* __restrict__ iS,
    float* __restrict__ dF, int* __restrict__ iF,
    int do_rows)
{
    int half    = do_rows ? (gridDim.x >> 1) : gridDim.x;
    bool isRow  = do_rows && ((int)blockIdx.x < half);
    int dirBlk  = isRow ? blockIdx.x : (blockIdx.x - (do_rows ? half : 0));

    const float4* own = isRow ? pkG : pkP;
    const float4* oth = isRow ? pkP : pkG;
    const int* exOwn0 = isRow ? is0 : if0;
    const int* exOwn1 = isRow ? is1 : if1;
    const int* exOwn2 = isRow ? is2 : if2;
    const int* exOth0 = isRow ? if0 : is0;
    const int* exOth1 = isRow ? if1 : is1;
    const int* exOth2 = isRow ? if2 : is2;
    float* dOut = isRow ? dS : dF;
    int*   iOut = isRow ? iS : iF;

    int lane = threadIdx.x & 63;
    int wave = threadIdx.x >> 6;
    int ownBase = dirBlk * 16 + wave * 4;
    int b = ownBase >> 12;
    int obase = b << 12;

    float ox[4], oy[4], oz[4], orr[4];
    int ownIn[4];
    int oe0[4], oe1[4], oe2[4];
    #pragma unroll
    for (int r = 0; r < 4; ++r) {
        float4 p = own[ownBase + r];
        ox[r] = p.x; oy[r] = p.y; oz[r] = p.z; orr[r] = p.w;
        ownIn[r] = (ownBase & (NPTS - 1)) + r;
        oe0[r] = 0; oe1[r] = 0; oe2[r] = 0;
        if (R > 0) oe0[r] = exOwn0[ownBase + r];
        if (R > 1) oe1[r] = exOwn1[ownBase + r];
        if (R > 2) oe2[r] = exOwn2[ownBase + r];
    }

    float best[4]; int bidx[4];
    #pragma unroll
    for (int r = 0; r < 4; ++r) { best[r] = FLT_MAX; bidx[r] = 0; }

    for (int j = lane; j < NPTS; j += 64) {
        float4 q = oth[obase + j];
        int eo0 = 0, eo1 = 0, eo2 = 0;
        if (R > 0) eo0 = exOth0[obase + j];
        if (R > 1) eo1 = exOth1[obase + j];
        if (R > 2) eo2 = exOth2[obase + j];
        #pragma unroll
        for (int r = 0; r < 4; ++r) {
            float zz = __fadd_rn(__fadd_rn(__fmul_rn(ox[r], q.x),
                                           __fmul_rn(oy[r], q.y)),
                                 __fmul_rn(oz[r], q.z));
            float d = __fmaf_rn(-2.0f, zz, __fadd_rn(orr[r], q.w));
            bool ex = false;
            if (R > 0) ex = ex || (j == oe0[r]) || (eo0 == ownIn[r]);
            if (R > 1) ex = ex || (j == oe1[r]) || (eo1 == ownIn[r]);
            if (R > 2) ex = ex || (j == oe2[r]) || (eo2 == ownIn[r]);
            if (ex) d = FLT_MAX;
            if (d < best[r]) { best[r] = d; bidx[r] = j; }
        }
    }

    #pragma unroll
    for (int r = 0; r < 4; ++r) {
        float v = best[r]; int ix = bidx[r];
        #pragma unroll
        for (int off = 32; off > 0; off >>= 1) {
            float v2 = __shfl_xor(v, off);
            int   i2 = __shfl_xor(ix, off);
            if (v2 < v || (v2 == v && i2 < ix)) { v = v2; ix = i2; }
        }
        if (lane == 0) {
            iOut[ownBase + r] = ix;
            if (dOut) dOut[ownBase + r] = v;
        }
    }
}

// ---------------------------------------------------------------------------
// Kernel: per-(batch, segment) partial sums (unchanged, verified).
// ---------------------------------------------------------------------------
__global__ __launch_bounds__(256) void normal_kernel(
    const float* __restrict__ preds, const float* __restrict__ normals,
    const float* __restrict__ dS, const float* __restrict__ dF,
    const int* __restrict__ if0, const int* __restrict__ if1,
    const int* __restrict__ if2, const int* __restrict__ if3,
    float4* __restrict__ partials)
{
    int b   = blockIdx.x >> 2;
    int seg = blockIdx.x & 3;
    int t   = threadIdx.x;

    const float* pp = preds + (size_t)b * NPTS * 3;
    float champ = 0.f, s1 = 0.f, s2 = 0.f, s3 = 0.f;

    for (int it = 0; it < 4; ++it) {
        int m  = seg * 1024 + it * 256 + t;
        int gi = b * NPTS + m;
        champ += dF[gi] + dS[gi];

        int i0 = if0[gi];
        float p0x = pp[3 * i0 + 0], p0y = pp[3 * i0 + 1], p0z = pp[3 * i0 + 2];
        float nx = normals[3 * gi + 0], ny = normals[3 * gi + 1], nz = normals[3 * gi + 2];

        int iA = if1[gi];
        s1 += (p0x - pp[3 * iA + 0]) * nx + (p0y - pp[3 * iA + 1]) * ny + (p0z - pp[3 * iA + 2]) * nz;
        int iB = if2[gi];
        s2 += (p0x - pp[3 * iB + 0]) * nx + (p0y - pp[3 * iB + 1]) * ny + (p0z - pp[3 * iB + 2]) * nz;
        int iC = if3[gi];
        s3 += (p0x - pp[3 * iC + 0]) * nx + (p0y - pp[3 * iC + 1]) * ny + (p0z - pp[3 * iC + 2]) * nz;
    }

    #pragma unroll
    for (int off = 32; off > 0; off >>= 1) {
        champ += __shfl_xor(champ, off);
        s1    += __shfl_xor(s1, off);
        s2    += __shfl_xor(s2, off);
        s3    += __shfl_xor(s3, off);
    }
    __shared__ float4 red[4];
    int wave = t >> 6, lane = t & 63;
    if (lane == 0) red[wave] = make_float4(champ, s1, s2, s3);
    __syncthreads();
    if (t == 0) {
        float4 a = red[0];
        for (int w = 1; w < 4; ++w) {
            a.x += red[w].x; a.y += red[w].y; a.z += red[w].z; a.w += red[w].w;
        }
        partials[blockIdx.x] = a;
    }
}

__global__ void final_kernel(const float4* __restrict__ partials, float* __restrict__ out)
{
    if (blockIdx.x == 0 && threadIdx.x == 0) {
        float champ = 0.f;
        float s[BATCH][3];
        for (int b = 0; b < BATCH; ++b) for (int k = 0; k < 3; ++k) s[b][k] = 0.f;
        for (int blk = 0; blk < 16; ++blk) {
            float4 p = partials[blk];
            int b = blk >> 2;
            champ   += p.x;
            s[b][0] += p.y;
            s[b][1] += p.z;
            s[b][2] += p.w;
        }
        float nl = 0.f;
        for (int k = 0; k < 3; ++k)
            for (int b = 0; b < BATCH; ++b)
                nl += fabsf(s[b][k]);
        out[0] = 1.0f + champ + 10.0f * nl;
    }
}

// ---------------------------------------------------------------------------
// Launch. Workspace layout (~5.1 MB with stripes):
//   pkG f4[16384] | pkP f4[16384] | iS0..iS2, iF0..iF3 int[16384] each |
//   dS0, dF0 float[16384] | partials f4[16] | stripes int2[2*16384*16]
// ---------------------------------------------------------------------------
extern "C" void kernel_launch(void* const* d_in, const int* in_sizes, int n_in,
                              void* d_out, int out_size, void* d_ws, size_t ws_size,
                              hipStream_t stream) {
    const float* gts     = (const float*)d_in[0];
    const float* preds   = (const float*)d_in[1];
    const float* normals = (const float*)d_in[2];
    float* out = (float*)d_out;

    char* ws = (char*)d_ws;
    float4* pkG = (float4*)ws;
    float4* pkP = (float4*)(ws + 262144);
    int* iS0 = (int*)(ws + 524288);
    int* iS1 = iS0 + TOT;
    int* iS2 = iS1 + TOT;
    int* iF0 = iS2 + TOT;
    int* iF1 = iF0 + TOT;
    int* iF2 = iF1 + TOT;
    int* iF3 = iF2 + TOT;
    float* dS0 = (float*)(iF3 + TOT);
    float* dF0 = dS0 + TOT;
    float4* partials = (float4*)(dF0 + TOT);
    size_t stripeOfs = 524288 + 9 * 65536 + 256;        // 1,114,368 (8-aligned)
    int2* stripes = (int2*)(ws + stripeOfs);
    size_t need = stripeOfs + (size_t)2 * TOT * NSTRIPE * sizeof(int2);  // ~5.3 MB

    pack_kernel<<<(2 * TOT + 255) / 256, 256, 0, stream>>>(gts, preds, pkG, pkP);

    if (ws_size >= need) {
        // Round 0: full scan both directions, 8 rows/wave, store stripe partials.
        round0_kernel<<<1024, 256, 0, stream>>>(pkG, pkP, dS0, iS0, dF0, iF0, stripes);

        // Rounds 1-2: both directions via stripe invalidation.
        roundR_kernel<1><<<8192, 256, 0, stream>>>(pkG, pkP, stripes,
            iS0, nullptr, nullptr, iF0, nullptr, nullptr, iS1, iF1, 1);
        roundR_kernel<2><<<8192, 256, 0, stream>>>(pkG, pkP, stripes,
            iS0, iS1, nullptr, iF0, iF1, nullptr, iS2, iF2, 1);
        // Round 3: col direction only (only i_f2s_3 is consumed).
        roundR_kernel<3><<<4096, 256, 0, stream>>>(pkG, pkP, stripes,
            iS0, iS1, iS2, iF0, iF1, iF2, nullptr, iF3, 0);
    } else {
        // Fallback: verified full-rescan path.
        round_full_kernel<0><<<2048, 256, 0, stream>>>(pkG, pkP,
            nullptr, nullptr, nullptr, nullptr, nullptr, nullptr,
            dS0, iS0, dF0, iF0, 1);
        round_full_kernel<1><<<2048, 256, 0, stream>>>(pkG, pkP,
            iS0, nullptr, nullptr, iF0, nullptr, nullptr,
            nullptr, iS1, nullptr, iF1, 1);
        round_full_kernel<2><<<2048, 256, 0, stream>>>(pkG, pkP,
            iS0, iS1, nullptr, iF0, iF1, nullptr,
            nullptr, iS2, nullptr, iF2, 1);
        round_full_kernel<3><<<1024, 256, 0, stream>>>(pkG, pkP,
            iS0, iS1, iS2, iF0, iF1, iF2,
            nullptr, nullptr, nullptr, iF3, 0);
    }

    normal_kernel<<<16, 256, 0, stream>>>(preds, normals, dS0, dF0,
                                          iF0, iF1, iF2, iF3, partials);
    final_kernel<<<1, 64, 0, stream>>>(partials, out);
}

// Round 6
// 170.591 us; speedup vs baseline: 2.2286x; 2.2286x over previous
//
#include <hip/hip_runtime.h>
#include <hip/hip_bf16.h>
#include <float.h>
#include <stdint.h>

// Problem constants (fixed by setup_inputs): B=4, N=M=4096, D=3.
#define BATCH 4
#define NPTS  4096
#define TOT   (BATCH * NPTS)   // 16384
#define NSTRIPE 16             // stripe s = {j : j % 16 == s}, 256 members each

// ---------------------------------------------------------------------------
// Kernel 1: pack points into float4 {x, y, z, |p|^2}, plus a stripe-major
// transposed copy pkT[b][s][k] = pk[b][s + 16k] so stripe rescans in rounds
// 1-3 read coalesced (consecutive lanes -> consecutive float4s).
// rr is x*x + y*y + z*z left-to-right, matching jnp.sum(x*x, -1).
// ---------------------------------------------------------------------------
__global__ __launch_bounds__(256) void pack_kernel(
    const float* __restrict__ gts, const float* __restrict__ preds,
    float4* __restrict__ pkG, float4* __restrict__ pkP,
    float4* __restrict__ pkGT, float4* __restrict__ pkPT)
{
    int i = blockIdx.x * blockDim.x + threadIdx.x;   // 0 .. 2*TOT-1
    if (i >= 2 * TOT) return;
    const float* src = (i < TOT) ? gts : preds;
    float4* dst      = (i < TOT) ? pkG : pkP;
    float4* dstT     = (i < TOT) ? pkGT : pkPT;
    int k            = (i < TOT) ? i : i - TOT;
    float x = src[3 * k + 0];
    float y = src[3 * k + 1];
    float z = src[3 * k + 2];
    float rr = __fadd_rn(__fadd_rn(__fmul_rn(x, x), __fmul_rn(y, y)), __fmul_rn(z, z));
    float4 v = make_float4(x, y, z, rr);
    dst[k] = v;
    int b = k >> 12, n = k & (NPTS - 1);
    dstT[(b << 12) + ((n & 15) << 8) + (n >> 4)] = v;
}

// ---------------------------------------------------------------------------
// Round 0 (full scan, both directions) + stripe-partial store.
// 8 rows per wave; lane l scans j ≡ l (mod 64), strict '<' keeps smallest-j
// min per lane. Butterfly xor{16,32} first: lane l then holds the min over
// stripe (l & 15); lanes 0-15 store the 16 stripe partials. Continue
// xor{1..8} for the global (d, idx). Lexicographic = numpy argmin tie-break.
// Lane 0 also writes the transposed index copy for round-1's coalesced rescan.
// ---------------------------------------------------------------------------
__global__ __launch_bounds__(256) void round0_kernel(
    const float4* __restrict__ pkG, const float4* __restrict__ pkP,
    float* __restrict__ dS, int* __restrict__ iS,
    float* __restrict__ dF, int* __restrict__ iF,
    int* __restrict__ iST, int* __restrict__ iFT,
    int2* __restrict__ stripes)   // [2][TOT][NSTRIPE]
{
    int wid  = blockIdx.x * 4 + (threadIdx.x >> 6);   // 0..4095
    int lane = threadIdx.x & 63;
    bool isRow = wid < 2048;
    int w = isRow ? wid : wid - 2048;
    int ownBase = w * 8;                 // 8 | 4096 -> no batch straddle
    int b = ownBase >> 12;
    int obase = b << 12;

    const float4* own = isRow ? pkG : pkP;
    const float4* oth = isRow ? pkP : pkG;
    float* dOut = isRow ? dS : dF;
    int*   iOut = isRow ? iS : iF;
    int*   iOutT = isRow ? iST : iFT;
    int dirOfs  = isRow ? 0 : TOT;

    float ox[8], oy[8], oz[8], orr[8];
    #pragma unroll
    for (int r = 0; r < 8; ++r) {
        float4 p = own[ownBase + r];
        ox[r] = p.x; oy[r] = p.y; oz[r] = p.z; orr[r] = p.w;
    }
    float best[8]; int bidx[8];
    #pragma unroll
    for (int r = 0; r < 8; ++r) { best[r] = FLT_MAX; bidx[r] = 0; }

    const float4* qp = oth + obase + lane;
    #pragma unroll 2
    for (int t = 0; t < 64; ++t) {
        float4 q = qp[t * 64];
        int j = lane + (t << 6);
        #pragma unroll
        for (int r = 0; r < 8; ++r) {
            // zz left-to-right, no contraction (verified bit-exact vs ref)
            float zz = __fadd_rn(__fadd_rn(__fmul_rn(ox[r], q.x),
                                           __fmul_rn(oy[r], q.y)),
                                 __fmul_rn(oz[r], q.z));
            // fma(-2,zz,s) == s - 2*zz (2*zz exact)
            float d = __fmaf_rn(-2.0f, zz, __fadd_rn(orr[r], q.w));
            if (d < best[r]) { best[r] = d; bidx[r] = j; }
        }
    }

    #pragma unroll
    for (int r = 0; r < 8; ++r) {
        float v = best[r]; int ix = bidx[r];
        #pragma unroll
        for (int off = 16; off <= 32; off <<= 1) {
            float v2 = __shfl_xor(v, off);
            int   i2 = __shfl_xor(ix, off);
            if (v2 < v || (v2 == v && i2 < ix)) { v = v2; ix = i2; }
        }
        if (lane < NSTRIPE)
            stripes[((size_t)(dirOfs + ownBase + r) << 4) + lane] =
                make_int2(__float_as_int(v), ix);
        #pragma unroll
        for (int off = 1; off <= 8; off <<= 1) {
            float v2 = __shfl_xor(v, off);
            int   i2 = __shfl_xor(ix, off);
            if (v2 < v || (v2 == v && i2 < ix)) { v = v2; ix = i2; }
        }
        if (lane == 0) {
            iOut[ownBase + r] = ix;
            dOut[ownBase + r] = v;
            int nl = (ownBase & (NPTS - 1)) + r;
            iOutT[obase + ((nl & 15) << 8) + (nl >> 4)] = ix;
        }
    }
}

// ---------------------------------------------------------------------------
// Rounds 1-3 via stripe invalidation. One wave per (direction, own point).
// A stored stripe min stays valid under the cumulative exclusion set unless
// its WINNER is excluded (removing non-winners can only raise the min, and
// the winner is the smallest-index minimizer). Invalid stripes are rescanned
// with full exclusion tests, reading the stripe-major transposed copies so
// all loads are coalesced. Exclusion of candidate j for own i (row dir; col
// mirrors): j == i_s2f_t[i]  OR  i_f2s_t[j] == i, any t < R.
// ---------------------------------------------------------------------------
template<int R>
__global__ __launch_bounds__(256) void roundR_kernel(
    const float4* __restrict__ pkG, const float4* __restrict__ pkP,
    const float4* __restrict__ pkGT, const float4* __restrict__ pkPT,
    const int2* __restrict__ stripes,
    const int* __restrict__ is0, const int* __restrict__ is1, const int* __restrict__ is2,
    const int* __restrict__ if0, const int* __restrict__ if1, const int* __restrict__ if2,
    const int* __restrict__ is0T, const int* __restrict__ is1T, const int* __restrict__ is2T,
    const int* __restrict__ if0T, const int* __restrict__ if1T, const int* __restrict__ if2T,
    int* __restrict__ iS, int* __restrict__ iF,
    int* __restrict__ iST, int* __restrict__ iFT,
    int do_rows)
{
    int wid  = blockIdx.x * 4 + (threadIdx.x >> 6);
    int lane = threadIdx.x & 63;
    int half = do_rows ? TOT : 0;
    bool isRow = wid < half;
    int i = isRow ? wid : wid - half;        // global own index, 0..TOT-1

    const float4* ownp = isRow ? pkG : pkP;
    const float4* othT = isRow ? pkPT : pkGT;
    const int* exOwn0 = isRow ? is0 : if0;
    const int* exOwn1 = isRow ? is1 : if1;
    const int* exOwn2 = isRow ? is2 : if2;
    const int* exOth0 = isRow ? if0 : is0;
    const int* exOth1 = isRow ? if1 : is1;
    const int* exOth2 = isRow ? if2 : is2;
    const int* exOth0T = isRow ? if0T : is0T;
    const int* exOth1T = isRow ? if1T : is1T;
    const int* exOth2T = isRow ? if2T : is2T;
    int* iOut  = isRow ? iS : iF;
    int* iOutT = isRow ? iST : iFT;
    int dirOfs = isRow ? 0 : TOT;

    int b = i >> 12;
    int obase = b << 12;
    int ownIn = i & (NPTS - 1);

    int e0 = exOwn0[i];
    int e1 = (R > 1) ? exOwn1[i] : -1;
    int e2 = (R > 2) ? exOwn2[i] : -1;

    bool excl = false;
    int2 key = make_int2(0, 0);
    if (lane < NSTRIPE) {
        key = stripes[((size_t)(dirOfs + i) << 4) + lane];
        int jw = key.y;
        excl = (jw == e0) || (exOth0[obase + jw] == ownIn);
        if (R > 1) excl = excl || (jw == e1) || (exOth1[obase + jw] == ownIn);
        if (R > 2) excl = excl || (jw == e2) || (exOth2[obase + jw] == ownIn);
    }
    unsigned long long mask = __ballot(excl);   // only lanes < 16 can be set

    float kd = (lane < NSTRIPE && !excl) ? __int_as_float(key.x) : FLT_MAX;
    int   kj = (lane < NSTRIPE && !excl) ? key.y : 0x7FFFFFFF;

    if (mask) {
        float4 p = ownp[i];
        const float4* tpB = othT + obase;
        const int* x0 = exOth0T + obase;
        const int* x1 = exOth1T + obase;   // valid only if R > 1
        const int* x2 = exOth2T + obase;   // valid only if R > 2
        while (mask) {
            int s = __ffsll(mask) - 1;          // wave-uniform
            mask &= mask - 1;
            int sb = s << 8;
            #pragma unroll
            for (int it = 0; it < 4; ++it) {
                int k = (it << 6) + lane;        // 0..255, coalesced
                int j = s + (k << 4);            // original other-index
                float4 q = tpB[sb + k];
                float zz = __fadd_rn(__fadd_rn(__fmul_rn(p.x, q.x),
                                               __fmul_rn(p.y, q.y)),
                                     __fmul_rn(p.z, q.z));
                float d = __fmaf_rn(-2.0f, zz, __fadd_rn(p.w, q.w));
                bool ex = (j == e0) || (x0[sb + k] == ownIn);
                if (R > 1) ex = ex || (j == e1) || (x1[sb + k] == ownIn);
                if (R > 2) ex = ex || (j == e2) || (x2[sb + k] == ownIn);
                if (!ex && (d < kd || (d == kd && j < kj))) { kd = d; kj = j; }
            }
        }
    }

    #pragma unroll
    for (int off = 1; off < 64; off <<= 1) {
        float v2 = __shfl_xor(kd, off);
        int   i2 = __shfl_xor(kj, off);
        if (v2 < kd || (v2 == kd && i2 < kj)) { kd = v2; kj = i2; }
    }
    if (lane == 0) {
        iOut[i] = kj;
        if (iOutT) iOutT[obase + ((ownIn & 15) << 8) + (ownIn >> 4)] = kj;
    }
}

// ---------------------------------------------------------------------------
// Fallback full-rescan kernel (verified) — used only if ws_size is too small.
// ---------------------------------------------------------------------------
template<int R>
__global__ __launch_bounds__(256) void round_full_kernel(
    const float4* __restrict__ pkG, const float4* __restrict__ pkP,
    const int* __restrict__ is0, const int* __restrict__ is1, const int* __restrict__ is2,
    const int* __restrict__ if0, const int* __restrict__ if1, const int* __restrict__ if2,
    float* __restrict__ dS, int* __restrict__ iS,
    float* __restrict__ dF, int* __restrict__ iF,
    int do_rows)
{
    int half    = do_rows ? (gridDim.x >> 1) : gridDim.x;
    bool isRow  = do_rows && ((int)blockIdx.x < half);
    int dirBlk  = isRow ? blockIdx.x : (blockIdx.x - (do_rows ? half : 0));

    const float4* own = isRow ? pkG : pkP;
    const float4* oth = isRow ? pkP : pkG;
    const int* exOwn0 = isRow ? is0 : if0;
    const int* exOwn1 = isRow ? is1 : if1;
    const int* exOwn2 = isRow ? is2 : if2;
    const int* exOth0 = isRow ? if0 : is0;
    const int* exOth1 = isRow ? if1 : is1;
    const int* exOth2 = isRow ? if2 : is2;
    float* dOut = isRow ? dS : dF;
    int*   iOut = isRow ? iS : iF;

    int lane = threadIdx.x & 63;
    int wave = threadIdx.x >> 6;
    int ownBase = dirBlk * 16 + wave * 4;
    int b = ownBase >> 12;
    int obase = b << 12;

    float ox[4], oy[4], oz[4], orr[4];
    int ownIn[4];
    int oe0[4], oe1[4], oe2[4];
    #pragma unroll
    for (int r = 0; r < 4; ++r) {
        float4 p = own[ownBase + r];
        ox[r] = p.x; oy[r] = p.y; oz[r] = p.z; orr[r] = p.w;
        ownIn[r] = (ownBase & (NPTS - 1)) + r;
        oe0[r] = 0; oe1[r] = 0; oe2[r] = 0;
        if (R > 0) oe0[r] = exOwn0[ownBase + r];
        if (R > 1) oe1[r] = exOwn1[ownBase + r];
        if (R > 2) oe2[r] = exOwn2[ownBase + r];
    }

    float best[4]; int bidx[4];
    #pragma unroll
    for (int r = 0; r < 4; ++r) { best[r] = FLT_MAX; bidx[r] = 0; }

    for (int j = lane; j < NPTS; j += 64) {
        float4 q = oth[obase + j];
        int eo0 = 0, eo1 = 0, eo2 = 0;
        if (R > 0) eo0 = exOth0[obase + j];
        if (R > 1) eo1 = exOth1[obase + j];
        if (R > 2) eo2 = exOth2[obase + j];
        #pragma unroll
        for (int r = 0; r < 4; ++r) {
            float zz = __fadd_rn(__fadd_rn(__fmul_rn(ox[r], q.x),
                                           __fmul_rn(oy[r], q.y)),
                                 __fmul_rn(oz[r], q.z));
            float d = __fmaf_rn(-2.0f, zz, __fadd_rn(orr[r], q.w));
            bool ex = false;
            if (R > 0) ex = ex || (j == oe0[r]) || (eo0 == ownIn[r]);
            if (R > 1) ex = ex || (j == oe1[r]) || (eo1 == ownIn[r]);
            if (R > 2) ex = ex || (j == oe2[r]) || (eo2 == ownIn[r]);
            if (ex) d = FLT_MAX;
            if (d < best[r]) { best[r] = d; bidx[r] = j; }
        }
    }

    #pragma unroll
    for (int r = 0; r < 4; ++r) {
        float v = best[r]; int ix = bidx[r];
        #pragma unroll
        for (int off = 32; off > 0; off >>= 1) {
            float v2 = __shfl_xor(v, off);
            int   i2 = __shfl_xor(ix, off);
            if (v2 < v || (v2 == v && i2 < ix)) { v = v2; ix = i2; }
        }
        if (lane == 0) {
            iOut[ownBase + r] = ix;
            if (dOut) dOut[ownBase + r] = v;
        }
    }
}

// ---------------------------------------------------------------------------
// Per-(batch, segment) partial sums (unchanged, verified).
// ---------------------------------------------------------------------------
__global__ __launch_bounds__(256) void normal_kernel(
    const float* __restrict__ preds, const float* __restrict__ normals,
    const float* __restrict__ dS, const float* __restrict__ dF,
    const int* __restrict__ if0, const int* __restrict__ if1,
    const int* __restrict__ if2, const int* __restrict__ if3,
    float4* __restrict__ partials)
{
    int b   = blockIdx.x >> 2;
    int seg = blockIdx.x & 3;
    int t   = threadIdx.x;

    const float* pp = preds + (size_t)b * NPTS * 3;
    float champ = 0.f, s1 = 0.f, s2 = 0.f, s3 = 0.f;

    for (int it = 0; it < 4; ++it) {
        int m  = seg * 1024 + it * 256 + t;
        int gi = b * NPTS + m;
        champ += dF[gi] + dS[gi];

        int i0 = if0[gi];
        float p0x = pp[3 * i0 + 0], p0y = pp[3 * i0 + 1], p0z = pp[3 * i0 + 2];
        float nx = normals[3 * gi + 0], ny = normals[3 * gi + 1], nz = normals[3 * gi + 2];

        int iA = if1[gi];
        s1 += (p0x - pp[3 * iA + 0]) * nx + (p0y - pp[3 * iA + 1]) * ny + (p0z - pp[3 * iA + 2]) * nz;
        int iB = if2[gi];
        s2 += (p0x - pp[3 * iB + 0]) * nx + (p0y - pp[3 * iB + 1]) * ny + (p0z - pp[3 * iB + 2]) * nz;
        int iC = if3[gi];
        s3 += (p0x - pp[3 * iC + 0]) * nx + (p0y - pp[3 * iC + 1]) * ny + (p0z - pp[3 * iC + 2]) * nz;
    }

    #pragma unroll
    for (int off = 32; off > 0; off >>= 1) {
        champ += __shfl_xor(champ, off);
        s1    += __shfl_xor(s1, off);
        s2    += __shfl_xor(s2, off);
        s3    += __shfl_xor(s3, off);
    }
    __shared__ float4 red[4];
    int wave = t >> 6, lane = t & 63;
    if (lane == 0) red[wave] = make_float4(champ, s1, s2, s3);
    __syncthreads();
    if (t == 0) {
        float4 a = red[0];
        for (int w = 1; w < 4; ++w) {
            a.x += red[w].x; a.y += red[w].y; a.z += red[w].z; a.w += red[w].w;
        }
        partials[blockIdx.x] = a;
    }
}

__global__ void final_kernel(const float4* __restrict__ partials, float* __restrict__ out)
{
    if (blockIdx.x == 0 && threadIdx.x == 0) {
        float champ = 0.f;
        float s[BATCH][3];
        for (int b = 0; b < BATCH; ++b) for (int k = 0; k < 3; ++k) s[b][k] = 0.f;
        for (int blk = 0; blk < 16; ++blk) {
            float4 p = partials[blk];
            int b = blk >> 2;
            champ   += p.x;
            s[b][0] += p.y;
            s[b][1] += p.z;
            s[b][2] += p.w;
        }
        float nl = 0.f;
        for (int k = 0; k < 3; ++k)
            for (int b = 0; b < BATCH; ++b)
                nl += fabsf(s[b][k]);
        out[0] = 1.0f + champ + 10.0f * nl;
    }
}

// ---------------------------------------------------------------------------
// Launch. Workspace layout (~6.0 MB with stripes + transposed copies):
//   pkG | pkP | pkGT | pkPT (256 KB each)
//   iS0..iS2, iF0..iF3 (7 x 64 KB) | dS0 | dF0 | partials
//   iS0T..iS2T, iF0T..iF2T (6 x 64 KB) | stripes (4 MB)
// ---------------------------------------------------------------------------
extern "C" void kernel_launch(void* const* d_in, const int* in_sizes, int n_in,
                              void* d_out, int out_size, void* d_ws, size_t ws_size,
                              hipStream_t stream) {
    const float* gts     = (const float*)d_in[0];
    const float* preds   = (const float*)d_in[1];
    const float* normals = (const float*)d_in[2];
    float* out = (float*)d_out;

    char* ws = (char*)d_ws;
    float4* pkG  = (float4*)ws;
    float4* pkP  = (float4*)(ws + 262144);
    float4* pkGT = (float4*)(ws + 524288);
    float4* pkPT = (float4*)(ws + 786432);
    int* iS0 = (int*)(ws + 1048576);
    int* iS1 = iS0 + TOT;
    int* iS2 = iS1 + TOT;
    int* iF0 = iS2 + TOT;
    int* iF1 = iF0 + TOT;
    int* iF2 = iF1 + TOT;
    int* iF3 = iF2 + TOT;
    float* dS0 = (float*)(iF3 + TOT);
    float* dF0 = dS0 + TOT;
    float4* partials = (float4*)(dF0 + TOT);
    int* iS0T = (int*)((char*)partials + 256);
    int* iS1T = iS0T + TOT;
    int* iS2T = iS1T + TOT;
    int* iF0T = iS2T + TOT;
    int* iF1T = iF0T + TOT;
    int* iF2T = iF1T + TOT;
    size_t stripeOfs = (size_t)((char*)(iF2T + TOT) - ws);  // 2,031,872 (8-aligned)
    int2* stripes = (int2*)(ws + stripeOfs);
    size_t need = stripeOfs + (size_t)2 * TOT * NSTRIPE * sizeof(int2);  // ~6.0 MB

    pack_kernel<<<(2 * TOT + 255) / 256, 256, 0, stream>>>(gts, preds, pkG, pkP, pkGT, pkPT);

    if (ws_size >= need) {
        // Round 0: full scan both directions, 8 rows/wave, store stripe partials.
        round0_kernel<<<1024, 256, 0, stream>>>(pkG, pkP, dS0, iS0, dF0, iF0,
                                                iS0T, iF0T, stripes);

        // Rounds 1-2: both directions via stripe invalidation (coalesced rescans).
        roundR_kernel<1><<<8192, 256, 0, stream>>>(pkG, pkP, pkGT, pkPT, stripes,
            iS0, nullptr, nullptr, iF0, nullptr, nullptr,
            iS0T, nullptr, nullptr, iF0T, nullptr, nullptr,
            iS1, iF1, iS1T, iF1T, 1);
        roundR_kernel<2><<<8192, 256, 0, stream>>>(pkG, pkP, pkGT, pkPT, stripes,
            iS0, iS1, nullptr, iF0, iF1, nullptr,
            iS0T, iS1T, nullptr, iF0T, iF1T, nullptr,
            iS2, iF2, iS2T, iF2T, 1);
        // Round 3: col direction only (only i_f2s_3 is consumed).
        roundR_kernel<3><<<4096, 256, 0, stream>>>(pkG, pkP, pkGT, pkPT, stripes,
            iS0, iS1, iS2, iF0, iF1, iF2,
            iS0T, iS1T, iS2T, iF0T, iF1T, iF2T,
            nullptr, iF3, nullptr, nullptr, 0);
    } else {
        // Fallback: verified full-rescan path.
        round_full_kernel<0><<<2048, 256, 0, stream>>>(pkG, pkP,
            nullptr, nullptr, nullptr, nullptr, nullptr, nullptr,
            dS0, iS0, dF0, iF0, 1);
        round_full_kernel<1><<<2048, 256, 0, stream>>>(pkG, pkP,
            iS0, nullptr, nullptr, iF0, nullptr, nullptr,
            nullptr, iS1, nullptr, iF1, 1);
        round_full_kernel<2><<<2048, 256, 0, stream>>>(pkG, pkP,
            iS0, iS1, nullptr, iF0, iF1, nullptr,
            nullptr, iS2, nullptr, iF2, 1);
        round_full_kernel<3><<<1024, 256, 0, stream>>>(pkG, pkP,
            iS0, iS1, iS2, iF0, iF1, iF2,
            nullptr, nullptr, nullptr, iF3, 0);
    }

    normal_kernel<<<16, 256, 0, stream>>>(preds, normals, dS0, dF0,
                                          iF0, iF1, iF2, iF3, partials);
    final_kernel<<<1, 64, 0, stream>>>(partials, out);
}

// Round 7
// 122.137 us; speedup vs baseline: 3.1127x; 1.3967x over previous
//
#include <hip/hip_runtime.h>
#include <hip/hip_bf16.h>
#include <float.h>
#include <stdint.h>

// Problem constants (fixed by setup_inputs): B=4, N=M=4096, D=3.
#define BATCH 4
#define NPTS  4096
#define TOT   (BATCH * NPTS)   // 16384

// Stripe scheme: stripe s = {j : j % NS == s}, M = NPTS/NS members each.
// Transposed slot of batch-local index n (member k of stripe s at s*M+k):
template<int NS>
__device__ __forceinline__ int tslot(int n) {
    constexpr int M = NPTS / NS;
    return (n & (NS - 1)) * M + (n / NS);
}

// ---------------------------------------------------------------------------
// Kernel 1: pack points into float4 {x, y, z, |p|^2}, plus a stripe-major
// transposed copy (layout depends on NS) so stripe rescans read coalesced.
// rr is x*x + y*y + z*z left-to-right, matching jnp.sum(x*x, -1).
// ---------------------------------------------------------------------------
template<int NS>
__global__ __launch_bounds__(256) void pack_kernel(
    const float* __restrict__ gts, const float* __restrict__ preds,
    float4* __restrict__ pkG, float4* __restrict__ pkP,
    float4* __restrict__ pkGT, float4* __restrict__ pkPT)
{
    int i = blockIdx.x * blockDim.x + threadIdx.x;   // 0 .. 2*TOT-1
    if (i >= 2 * TOT) return;
    const float* src = (i < TOT) ? gts : preds;
    float4* dst      = (i < TOT) ? pkG : pkP;
    float4* dstT     = (i < TOT) ? pkGT : pkPT;
    int k            = (i < TOT) ? i : i - TOT;
    float x = src[3 * k + 0];
    float y = src[3 * k + 1];
    float z = src[3 * k + 2];
    float rr = __fadd_rn(__fadd_rn(__fmul_rn(x, x), __fmul_rn(y, y)), __fmul_rn(z, z));
    float4 v = make_float4(x, y, z, rr);
    dst[k] = v;
    int b = k >> 12, n = k & (NPTS - 1);
    dstT[(b << 12) + tslot<NS>(n)] = v;
}

// ---------------------------------------------------------------------------
// Round 0 (full scan, both directions) + stripe-partial store.
// 8 rows per wave; lane l scans j ≡ l (mod 64), strict '<' keeps smallest-j
// min per lane. For NS=64 each lane IS a stripe; for NS<64 a pre-butterfly
// over offsets {NS..32} folds lanes into stripes first. Lanes <NS store the
// stripe partials; the remaining butterfly {1..NS/2} yields the global
// (d, idx). Lexicographic compare = numpy argmin tie-break throughout.
// ---------------------------------------------------------------------------
template<int NS>
__global__ __launch_bounds__(256) void round0_kernel(
    const float4* __restrict__ pkG, const float4* __restrict__ pkP,
    float* __restrict__ dS, int* __restrict__ iS,
    float* __restrict__ dF, int* __restrict__ iF,
    int* __restrict__ iST, int* __restrict__ iFT,
    int2* __restrict__ stripes)   // [2][TOT][NS]
{
    int wid  = blockIdx.x * 4 + (threadIdx.x >> 6);   // 0..4095
    int lane = threadIdx.x & 63;
    bool isRow = wid < 2048;
    int w = isRow ? wid : wid - 2048;
    int ownBase = w * 8;                 // 8 | 4096 -> no batch straddle
    int b = ownBase >> 12;
    int obase = b << 12;

    const float4* own = isRow ? pkG : pkP;
    const float4* oth = isRow ? pkP : pkG;
    float* dOut = isRow ? dS : dF;
    int*   iOut = isRow ? iS : iF;
    int*   iOutT = isRow ? iST : iFT;
    int dirOfs  = isRow ? 0 : TOT;

    float ox[8], oy[8], oz[8], orr[8];
    #pragma unroll
    for (int r = 0; r < 8; ++r) {
        float4 p = own[ownBase + r];
        ox[r] = p.x; oy[r] = p.y; oz[r] = p.z; orr[r] = p.w;
    }
    float best[8]; int bidx[8];
    #pragma unroll
    for (int r = 0; r < 8; ++r) { best[r] = FLT_MAX; bidx[r] = 0; }

    const float4* qp = oth + obase + lane;
    #pragma unroll 2
    for (int t = 0; t < 64; ++t) {
        float4 q = qp[t * 64];
        int j = lane + (t << 6);
        #pragma unroll
        for (int r = 0; r < 8; ++r) {
            // zz left-to-right, no contraction (verified bit-exact vs ref)
            float zz = __fadd_rn(__fadd_rn(__fmul_rn(ox[r], q.x),
                                           __fmul_rn(oy[r], q.y)),
                                 __fmul_rn(oz[r], q.z));
            // fma(-2,zz,s) == s - 2*zz (2*zz exact)
            float d = __fmaf_rn(-2.0f, zz, __fadd_rn(orr[r], q.w));
            if (d < best[r]) { best[r] = d; bidx[r] = j; }
        }
    }

    #pragma unroll
    for (int r = 0; r < 8; ++r) {
        float v = best[r]; int ix = bidx[r];
        #pragma unroll
        for (int off = NS; off <= 32; off <<= 1) {
            float v2 = __shfl_xor(v, off);
            int   i2 = __shfl_xor(ix, off);
            if (v2 < v || (v2 == v && i2 < ix)) { v = v2; ix = i2; }
        }
        if (lane < NS)
            stripes[(size_t)(dirOfs + ownBase + r) * NS + lane] =
                make_int2(__float_as_int(v), ix);
        #pragma unroll
        for (int off = 1; off < NS; off <<= 1) {
            float v2 = __shfl_xor(v, off);
            int   i2 = __shfl_xor(ix, off);
            if (v2 < v || (v2 == v && i2 < ix)) { v = v2; ix = i2; }
        }
        if (lane == 0) {
            iOut[ownBase + r] = ix;
            dOut[ownBase + r] = v;
            int nl = (ownBase & (NPTS - 1)) + r;
            iOutT[obase + tslot<NS>(nl)] = ix;
        }
    }
}

// ---------------------------------------------------------------------------
// Rounds 1-3, incremental stripe invalidation with WRITE-BACK.
// Invariant: at entry of round R, every stored stripe entry is the stripe's
// lex-min excluding the cumulative exclusion set E_{R-1} (round 0 stores
// E_0 = empty; rescans write back). So the check phase only tests each
// stripe winner against the NEW exclusions from round R-1:
//   jw == e_{R-1}  OR  exOth_{R-1}[jw] == ownIn.
// Valid winners stay exact (removing non-winners can only raise the min).
// Invalid stripes rescan their M members under the FULL cumulative set,
// reading transposed copies (coalesced), and write the result back.
// ---------------------------------------------------------------------------
template<int R, int NS>
__global__ __launch_bounds__(256) void roundR_kernel(
    const float4* __restrict__ pkG, const float4* __restrict__ pkP,
    const float4* __restrict__ pkGT, const float4* __restrict__ pkPT,
    int2* __restrict__ stripes,
    const int* __restrict__ is0, const int* __restrict__ is1, const int* __restrict__ is2,
    const int* __restrict__ if0, const int* __restrict__ if1, const int* __restrict__ if2,
    const int* __restrict__ is0T, const int* __restrict__ is1T, const int* __restrict__ is2T,
    const int* __restrict__ if0T, const int* __restrict__ if1T, const int* __restrict__ if2T,
    int* __restrict__ iS, int* __restrict__ iF,
    int* __restrict__ iST, int* __restrict__ iFT,
    int do_rows)
{
    constexpr int M = NPTS / NS;      // members per stripe
    constexpr int ITERS = M / 64;     // 64-lane passes per rescan

    int wid  = blockIdx.x * 4 + (threadIdx.x >> 6);
    int lane = threadIdx.x & 63;
    int half = do_rows ? TOT : 0;
    bool isRow = wid < half;
    int i = isRow ? wid : wid - half;        // global own index, 0..TOT-1

    const float4* ownp = isRow ? pkG : pkP;
    const float4* othT = isRow ? pkPT : pkGT;
    const int* exOwn0 = isRow ? is0 : if0;
    const int* exOwn1 = isRow ? is1 : if1;
    const int* exOwn2 = isRow ? is2 : if2;
    // newest reverse array (linear, for the winner check):
    const int* exNewLin = isRow ? (R == 1 ? if0 : R == 2 ? if1 : if2)
                                : (R == 1 ? is0 : R == 2 ? is1 : is2);
    const int* x0 = isRow ? if0T : is0T;     // transposed cumulative reverse
    const int* x1 = isRow ? if1T : is1T;
    const int* x2 = isRow ? if2T : is2T;
    int* iOut  = isRow ? iS : iF;
    int* iOutT = isRow ? iST : iFT;
    int dirOfs = isRow ? 0 : TOT;

    int b = i >> 12;
    int obase = b << 12;
    int ownIn = i & (NPTS - 1);

    int e0 = exOwn0[i];
    int e1 = (R > 1) ? exOwn1[i] : -1;
    int e2 = (R > 2) ? exOwn2[i] : -1;
    int eNew = (R == 1) ? e0 : (R == 2) ? e1 : e2;

    int2* myStripes = stripes + (size_t)(dirOfs + i) * NS;

    bool excl = false;
    int2 key = make_int2(0x7F7FFFFF, 0x7FFFFFFF);
    if (lane < NS) {
        key = myStripes[lane];
        int jw = key.y;
        if (jw < NPTS)   // sentinel (all-excluded stripe) can never win or change
            excl = (jw == eNew) || (exNewLin[obase + jw] == ownIn);
    }
    unsigned long long mask = __ballot(excl);

    float kd = (lane < NS && !excl) ? __int_as_float(key.x) : FLT_MAX;
    int   kj = (lane < NS && !excl) ? key.y : 0x7FFFFFFF;

    if (mask) {
        float4 p = ownp[i];
        const float4* tp = othT + obase;
        const int* x0b = x0 + obase;
        const int* x1b = x1 + obase;
        const int* x2b = x2 + obase;
        while (mask) {
            int s = __ffsll(mask) - 1;          // wave-uniform stripe id
            mask &= mask - 1;
            int sb = s * M;
            float rd = FLT_MAX; int rj = 0x7FFFFFFF;
            #pragma unroll
            for (int it = 0; it < ITERS; ++it) {
                int k = (it << 6) + lane;        // 0..M-1, coalesced
                int j = s + k * NS;              // original other-index
                float4 q = tp[sb + k];
                float zz = __fadd_rn(__fadd_rn(__fmul_rn(p.x, q.x),
                                               __fmul_rn(p.y, q.y)),
                                     __fmul_rn(p.z, q.z));
                float d = __fmaf_rn(-2.0f, zz, __fadd_rn(p.w, q.w));
                bool ex = (j == e0) || (x0b[sb + k] == ownIn);
                if (R > 1) ex = ex || (j == e1) || (x1b[sb + k] == ownIn);
                if (R > 2) ex = ex || (j == e2) || (x2b[sb + k] == ownIn);
                if (!ex && (d < rd || (d == rd && j < rj))) { rd = d; rj = j; }
            }
            #pragma unroll
            for (int off = 1; off < 64; off <<= 1) {
                float v2 = __shfl_xor(rd, off);
                int   i2 = __shfl_xor(rj, off);
                if (v2 < rd || (v2 == rd && i2 < rj)) { rd = v2; rj = i2; }
            }
            if (lane == s) {
                kd = rd; kj = rj;
                myStripes[s] = make_int2(__float_as_int(rd), rj);  // write-back
            }
        }
    }

    #pragma unroll
    for (int off = 1; off < 64; off <<= 1) {
        float v2 = __shfl_xor(kd, off);
        int   i2 = __shfl_xor(kj, off);
        if (v2 < kd || (v2 == kd && i2 < kj)) { kd = v2; kj = i2; }
    }
    if (lane == 0) {
        iOut[i] = kj;
        if (iOutT) iOutT[obase + tslot<NS>(ownIn)] = kj;
    }
}

// ---------------------------------------------------------------------------
// Fallback full-rescan kernel (verified) — used only if ws_size is too small.
// ---------------------------------------------------------------------------
template<int R>
__global__ __launch_bounds__(256) void round_full_kernel(
    const float4* __restrict__ pkG, const float4* __restrict__ pkP,
    const int* __restrict__ is0, const int* __restrict__ is1, const int* __restrict__ is2,
    const int* __restrict__ if0, const int* __restrict__ if1, const int* __restrict__ if2,
    float* __restrict__ dS, int* __restrict__ iS,
    float* __restrict__ dF, int* __restrict__ iF,
    int do_rows)
{
    int half    = do_rows ? (gridDim.x >> 1) : gridDim.x;
    bool isRow  = do_rows && ((int)blockIdx.x < half);
    int dirBlk  = isRow ? blockIdx.x : (blockIdx.x - (do_rows ? half : 0));

    const float4* own = isRow ? pkG : pkP;
    const float4* oth = isRow ? pkP : pkG;
    const int* exOwn0 = isRow ? is0 : if0;
    const int* exOwn1 = isRow ? is1 : if1;
    const int* exOwn2 = isRow ? is2 : if2;
    const int* exOth0 = isRow ? if0 : is0;
    const int* exOth1 = isRow ? if1 : is1;
    const int* exOth2 = isRow ? if2 : is2;
    float* dOut = isRow ? dS : dF;
    int*   iOut = isRow ? iS : iF;

    int lane = threadIdx.x & 63;
    int wave = threadIdx.x >> 6;
    int ownBase = dirBlk * 16 + wave * 4;
    int b = ownBase >> 12;
    int obase = b << 12;

    float ox[4], oy[4], oz[4], orr[4];
    int ownIn[4];
    int oe0[4], oe1[4], oe2[4];
    #pragma unroll
    for (int r = 0; r < 4; ++r) {
        float4 p = own[ownBase + r];
        ox[r] = p.x; oy[r] = p.y; oz[r] = p.z; orr[r] = p.w;
        ownIn[r] = (ownBase & (NPTS - 1)) + r;
        oe0[r] = 0; oe1[r] = 0; oe2[r] = 0;
        if (R > 0) oe0[r] = exOwn0[ownBase + r];
        if (R > 1) oe1[r] = exOwn1[ownBase + r];
        if (R > 2) oe2[r] = exOwn2[ownBase + r];
    }

    float best[4]; int bidx[4];
    #pragma unroll
    for (int r = 0; r < 4; ++r) { best[r] = FLT_MAX; bidx[r] = 0; }

    for (int j = lane; j < NPTS; j += 64) {
        float4 q = oth[obase + j];
        int eo0 = 0, eo1 = 0, eo2 = 0;
        if (R > 0) eo0 = exOth0[obase + j];
        if (R > 1) eo1 = exOth1[obase + j];
        if (R > 2) eo2 = exOth2[obase + j];
        #pragma unroll
        for (int r = 0; r < 4; ++r) {
            float zz = __fadd_rn(__fadd_rn(__fmul_rn(ox[r], q.x),
                                           __fmul_rn(oy[r], q.y)),
                                 __fmul_rn(oz[r], q.z));
            float d = __fmaf_rn(-2.0f, zz, __fadd_rn(orr[r], q.w));
            bool ex = false;
            if (R > 0) ex = ex || (j == oe0[r]) || (eo0 == ownIn[r]);
            if (R > 1) ex = ex || (j == oe1[r]) || (eo1 == ownIn[r]);
            if (R > 2) ex = ex || (j == oe2[r]) || (eo2 == ownIn[r]);
            if (ex) d = FLT_MAX;
            if (d < best[r]) { best[r] = d; bidx[r] = j; }
        }
    }

    #pragma unroll
    for (int r = 0; r < 4; ++r) {
        float v = best[r]; int ix = bidx[r];
        #pragma unroll
        for (int off = 32; off > 0; off >>= 1) {
            float v2 = __shfl_xor(v, off);
            int   i2 = __shfl_xor(ix, off);
            if (v2 < v || (v2 == v && i2 < ix)) { v = v2; ix = i2; }
        }
        if (lane == 0) {
            iOut[ownBase + r] = ix;
            if (dOut) dOut[ownBase + r] = v;
        }
    }
}

// ---------------------------------------------------------------------------
// Per-(batch, segment) partial sums (unchanged, verified).
// ---------------------------------------------------------------------------
__global__ __launch_bounds__(256) void normal_kernel(
    const float* __restrict__ preds, const float* __restrict__ normals,
    const float* __restrict__ dS, const float* __restrict__ dF,
    const int* __restrict__ if0, const int* __restrict__ if1,
    const int* __restrict__ if2, const int* __restrict__ if3,
    float4* __restrict__ partials)
{
    int b   = blockIdx.x >> 2;
    int seg = blockIdx.x & 3;
    int t   = threadIdx.x;

    const float* pp = preds + (size_t)b * NPTS * 3;
    float champ = 0.f, s1 = 0.f, s2 = 0.f, s3 = 0.f;

    for (int it = 0; it < 4; ++it) {
        int m  = seg * 1024 + it * 256 + t;
        int gi = b * NPTS + m;
        champ += dF[gi] + dS[gi];

        int i0 = if0[gi];
        float p0x = pp[3 * i0 + 0], p0y = pp[3 * i0 + 1], p0z = pp[3 * i0 + 2];
        float nx = normals[3 * gi + 0], ny = normals[3 * gi + 1], nz = normals[3 * gi + 2];

        int iA = if1[gi];
        s1 += (p0x - pp[3 * iA + 0]) * nx + (p0y - pp[3 * iA + 1]) * ny + (p0z - pp[3 * iA + 2]) * nz;
        int iB = if2[gi];
        s2 += (p0x - pp[3 * iB + 0]) * nx + (p0y - pp[3 * iB + 1]) * ny + (p0z - pp[3 * iB + 2]) * nz;
        int iC = if3[gi];
        s3 += (p0x - pp[3 * iC + 0]) * nx + (p0y - pp[3 * iC + 1]) * ny + (p0z - pp[3 * iC + 2]) * nz;
    }

    #pragma unroll
    for (int off = 32; off > 0; off >>= 1) {
        champ += __shfl_xor(champ, off);
        s1    += __shfl_xor(s1, off);
        s2    += __shfl_xor(s2, off);
        s3    += __shfl_xor(s3, off);
    }
    __shared__ float4 red[4];
    int wave = t >> 6, lane = t & 63;
    if (lane == 0) red[wave] = make_float4(champ, s1, s2, s3);
    __syncthreads();
    if (t == 0) {
        float4 a = red[0];
        for (int w = 1; w < 4; ++w) {
            a.x += red[w].x; a.y += red[w].y; a.z += red[w].z; a.w += red[w].w;
        }
        partials[blockIdx.x] = a;
    }
}

__global__ void final_kernel(const float4* __restrict__ partials, float* __restrict__ out)
{
    if (blockIdx.x == 0 && threadIdx.x == 0) {
        float champ = 0.f;
        float s[BATCH][3];
        for (int b = 0; b < BATCH; ++b) for (int k = 0; k < 3; ++k) s[b][k] = 0.f;
        for (int blk = 0; blk < 16; ++blk) {
            float4 p = partials[blk];
            int b = blk >> 2;
            champ   += p.x;
            s[b][0] += p.y;
            s[b][1] += p.z;
            s[b][2] += p.w;
        }
        float nl = 0.f;
        for (int k = 0; k < 3; ++k)
            for (int b = 0; b < BATCH; ++b)
                nl += fabsf(s[b][k]);
        out[0] = 1.0f + champ + 10.0f * nl;
    }
}

// ---------------------------------------------------------------------------
// Launch. Tiered by ws_size:
//   NS=64 (~18.8 MB): 1-pass rescans, incremental check   <- expected path
//   NS=16 (~6.0 MB):  4-pass rescans (R6-proven layout size)
//   else: verified full-rescan chain
// ---------------------------------------------------------------------------
extern "C" void kernel_launch(void* const* d_in, const int* in_sizes, int n_in,
                              void* d_out, int out_size, void* d_ws, size_t ws_size,
                              hipStream_t stream) {
    const float* gts     = (const float*)d_in[0];
    const float* preds   = (const float*)d_in[1];
    const float* normals = (const float*)d_in[2];
    float* out = (float*)d_out;

    char* ws = (char*)d_ws;
    float4* pkG  = (float4*)ws;
    float4* pkP  = (float4*)(ws + 262144);
    float4* pkGT = (float4*)(ws + 524288);
    float4* pkPT = (float4*)(ws + 786432);
    int* iS0 = (int*)(ws + 1048576);
    int* iS1 = iS0 + TOT;
    int* iS2 = iS1 + TOT;
    int* iF0 = iS2 + TOT;
    int* iF1 = iF0 + TOT;
    int* iF2 = iF1 + TOT;
    int* iF3 = iF2 + TOT;
    float* dS0 = (float*)(iF3 + TOT);
    float* dF0 = dS0 + TOT;
    float4* partials = (float4*)(dF0 + TOT);
    int* iS0T = (int*)((char*)partials + 256);
    int* iS1T = iS0T + TOT;
    int* iS2T = iS1T + TOT;
    int* iF0T = iS2T + TOT;
    int* iF1T = iF0T + TOT;
    int* iF2T = iF1T + TOT;
    size_t stripeOfs = (size_t)((char*)(iF2T + TOT) - ws);  // ~2.03 MB, 8-aligned
    int2* stripes = (int2*)(ws + stripeOfs);
    size_t need64 = stripeOfs + (size_t)2 * TOT * 64 * sizeof(int2);  // ~18.8 MB
    size_t need16 = stripeOfs + (size_t)2 * TOT * 16 * sizeof(int2);  // ~6.0 MB

    if (ws_size >= need64) {
        pack_kernel<64><<<(2 * TOT + 255) / 256, 256, 0, stream>>>(
            gts, preds, pkG, pkP, pkGT, pkPT);
        round0_kernel<64><<<1024, 256, 0, stream>>>(pkG, pkP, dS0, iS0, dF0, iF0,
                                                    iS0T, iF0T, stripes);
        roundR_kernel<1, 64><<<8192, 256, 0, stream>>>(pkG, pkP, pkGT, pkPT, stripes,
            iS0, iS1, iS2, iF0, iF1, iF2,
            iS0T, iS1T, iS2T, iF0T, iF1T, iF2T,
            iS1, iF1, iS1T, iF1T, 1);
        roundR_kernel<2, 64><<<8192, 256, 0, stream>>>(pkG, pkP, pkGT, pkPT, stripes,
            iS0, iS1, iS2, iF0, iF1, iF2,
            iS0T, iS1T, iS2T, iF0T, iF1T, iF2T,
            iS2, iF2, iS2T, iF2T, 1);
        roundR_kernel<3, 64><<<4096, 256, 0, stream>>>(pkG, pkP, pkGT, pkPT, stripes,
            iS0, iS1, iS2, iF0, iF1, iF2,
            iS0T, iS1T, iS2T, iF0T, iF1T, iF2T,
            nullptr, iF3, nullptr, nullptr, 0);
    } else if (ws_size >= need16) {
        pack_kernel<16><<<(2 * TOT + 255) / 256, 256, 0, stream>>>(
            gts, preds, pkG, pkP, pkGT, pkPT);
        round0_kernel<16><<<1024, 256, 0, stream>>>(pkG, pkP, dS0, iS0, dF0, iF0,
                                                    iS0T, iF0T, stripes);
        roundR_kernel<1, 16><<<8192, 256, 0, stream>>>(pkG, pkP, pkGT, pkPT, stripes,
            iS0, iS1, iS2, iF0, iF1, iF2,
            iS0T, iS1T, iS2T, iF0T, iF1T, iF2T,
            iS1, iF1, iS1T, iF1T, 1);
        roundR_kernel<2, 16><<<8192, 256, 0, stream>>>(pkG, pkP, pkGT, pkPT, stripes,
            iS0, iS1, iS2, iF0, iF1, iF2,
            iS0T, iS1T, iS2T, iF0T, iF1T, iF2T,
            iS2, iF2, iS2T, iF2T, 1);
        roundR_kernel<3, 16><<<4096, 256, 0, stream>>>(pkG, pkP, pkGT, pkPT, stripes,
            iS0, iS1, iS2, iF0, iF1, iF2,
            iS0T, iS1T, iS2T, iF0T, iF1T, iF2T,
            nullptr, iF3, nullptr, nullptr, 0);
    } else {
        pack_kernel<64><<<(2 * TOT + 255) / 256, 256, 0, stream>>>(
            gts, preds, pkG, pkP, pkGT, pkPT);
        round_full_kernel<0><<<2048, 256, 0, stream>>>(pkG, pkP,
            nullptr, nullptr, nullptr, nullptr, nullptr, nullptr,
            dS0, iS0, dF0, iF0, 1);
        round_full_kernel<1><<<2048, 256, 0, stream>>>(pkG, pkP,
            iS0, nullptr, nullptr, iF0, nullptr, nullptr,
            nullptr, iS1, nullptr, iF1, 1);
        round_full_kernel<2><<<2048, 256, 0, stream>>>(pkG, pkP,
            iS0, iS1, nullptr, iF0, iF1, nullptr,
            nullptr, iS2, nullptr, iF2, 1);
        round_full_kernel<3><<<1024, 256, 0, stream>>>(pkG, pkP,
            iS0, iS1, iS2, iF0, iF1, iF2,
            nullptr, nullptr, nullptr, iF3, 0);
    }

    normal_kernel<<<16, 256, 0, stream>>>(preds, normals, dS0, dF0,
                                          iF0, iF1, iF2, iF3, partials);
    final_kernel<<<1, 64, 0, stream>>>(partials, out);
}